// Round 13
// baseline (158.692 us; speedup 1.0000x reference)
//
#include <hip/hip_runtime.h>

#define N_USER 50000
#define N_ITEM 50000
#define N_EDGE 800000
#define D 128
#define NTOT   100000          // combined dst space: [0,50K)=items, [50K,100K)=users
#define NE2    1600000         // both directions' edges
#define BKT_SH 9               // 512 dsts per bucket
#define NBKT   196             // ceil(NTOT / 512)
#define CAP    12288           // LDS csr staging cap (bucket mean 8192, sigma ~90)

typedef __attribute__((ext_vector_type(8))) short     bf16x8;
typedef __attribute__((ext_vector_type(4))) float     f32x4;
typedef __attribute__((ext_vector_type(4))) unsigned short ushortx4;
typedef __attribute__((ext_vector_type(8))) unsigned short ushortx8;

__device__ __forceinline__ unsigned short f2bf(float f) {
    unsigned int u = __float_as_uint(f);
    unsigned int r = (u + 0x7fffu + ((u >> 16) & 1u)) >> 16;   // RNE
    return (unsigned short)r;
}
__device__ __forceinline__ float bf2f(unsigned short b) {
    return __uint_as_float(((unsigned int)b) << 16);
}

// ---------------------------------------------------------------------------
// MEGA kernel (block-range roles, all 256 thr). pack/packW/count are mutually
// independent -> count's latency hides under pack's copy traffic.
// ---------------------------------------------------------------------------
#define PACKA_BLOCKS 12500
#define PACKW_BLOCKS 32
#define CNT_BLOCKS   391   // ceil(NE2 / 4096)

__global__ __launch_bounds__(256) void mega3_kernel(
    const float* __restrict__ user_emb, const int* __restrict__ user_ids,
    const float* __restrict__ item_x,
    const int* __restrict__ edge_ui, const int* __restrict__ edge_iu,
    const float* __restrict__ Wl_ui, const float* __restrict__ Wr_ui,
    const float* __restrict__ Wl_iu, const float* __restrict__ Wr_iu,
    unsigned short* T_user, unsigned short* T_item,
    unsigned short* WfragUI, unsigned short* WfragIU,
    int* __restrict__ gcnt)
{
    const int b = blockIdx.x;
    const int tid = threadIdx.x;

    if (b < PACKA_BLOCKS) {
        int gid = b * 256 + tid;
        int row = gid >> 5;
        int c = (gid & 31) << 2;
        const float* src;
        unsigned short* dst;
        if (row < N_USER) {
            src = user_emb + (size_t)user_ids[row] * D;
            dst = T_user + (size_t)row * 128;
        } else {
            int r = row - N_USER;
            src = item_x + (size_t)r * D;
            dst = T_item + (size_t)r * 128;
        }
        const float4 v = *reinterpret_cast<const float4*>(src + c);
        ushortx4 o;
        o.x = f2bf(v.x); o.y = f2bf(v.y); o.z = f2bf(v.z); o.w = f2bf(v.w);
        *reinterpret_cast<ushortx4*>(dst + c) = o;
    } else if (b < PACKA_BLOCKS + PACKW_BLOCKS) {
        int id = (b - PACKA_BLOCKS) * 256 + tid;   // [0, 8192)
        const float *Wl, *Wr;
        unsigned short* Wf;
        if (id < 4096) { Wl = Wl_ui; Wr = Wr_ui; Wf = WfragUI; }
        else { id -= 4096; Wl = Wl_iu; Wr = Wr_iu; Wf = WfragIU; }
        int lane = id & 63;
        int c    = (id >> 6) & 7;
        int ks   = id >> 9;
        int col  = c * 16 + (lane & 15);
        int k0   = ks * 32 + (lane >> 4) * 8;
        ushortx8 o;
#pragma unroll
        for (int i = 0; i < 8; ++i) {
            int k = k0 + i;
            float f = (k < D) ? Wl[(size_t)k * D + col] : Wr[(size_t)(k - D) * D + col];
            o[i] = f2bf(f);
        }
        *reinterpret_cast<ushortx8*>(Wf + (size_t)id * 8) = o;
    } else {
        __shared__ int bcnt[NBKT];
        for (int i = tid; i < NBKT; i += 256) bcnt[i] = 0;
        __syncthreads();
        int e0 = (b - PACKA_BLOCKS - PACKW_BLOCKS) * 4096;
#pragma unroll
        for (int j = 0; j < 16; ++j) {
            int e = e0 + j * 256 + tid;
            if (e < NE2) {
                int d = (e < N_EDGE) ? edge_ui[N_EDGE + e]
                                     : (N_ITEM + edge_iu[N_EDGE + (e - N_EDGE)]);
                atomicAdd(&bcnt[d >> BKT_SH], 1);
            }
        }
        __syncthreads();
        for (int i = tid; i < NBKT; i += 256)
            if (bcnt[i]) atomicAdd(&gcnt[i], bcnt[i]);
    }
}

// ---------------------------------------------------------------------------
// Scan 196 bucket counts -> bucket bases; init bucket cursors.
// ---------------------------------------------------------------------------
__global__ __launch_bounds__(256) void bucketscan_kernel(
    const int* __restrict__ gcnt, int* __restrict__ bbase, int* __restrict__ bcur)
{
    __shared__ int s[256];
    int tid = threadIdx.x;
    int v = (tid < NBKT) ? gcnt[tid] : 0;
    s[tid] = v;
    __syncthreads();
    for (int d = 1; d < 256; d <<= 1) {
        int t = (tid >= d) ? s[tid - d] : 0;
        __syncthreads();
        s[tid] += t;
        __syncthreads();
    }
    if (tid < NBKT) {
        int base = s[tid] - v;     // exclusive
        bbase[tid] = base;
        bcur[tid]  = base;
    }
    if (tid == NBKT - 1) bbase[NBKT] = s[tid];
}

// ---------------------------------------------------------------------------
// Scatter records into bucket-segmented array. Record = src16 | dstlow9<<16.
// Rank captured from the pass-1 count atomic; final writes atomic-free.
// ---------------------------------------------------------------------------
#define B2_BLOCKS 196   // ceil(NE2 / 8192)

__global__ __launch_bounds__(1024) void scatter_records_kernel(
    const int* __restrict__ edge_ui, const int* __restrict__ edge_iu,
    int* __restrict__ bcur, unsigned int* __restrict__ records)
{
    __shared__ int bcnt[NBKT];
    __shared__ int bpos[NBKT];
    const int tid = threadIdx.x;
    for (int i = tid; i < NBKT; i += 1024) bcnt[i] = 0;
    __syncthreads();

    const int e0 = blockIdx.x * 8192;
    unsigned int rec[8];
    int bkt[8], rnk[8];
#pragma unroll
    for (int j = 0; j < 8; ++j) {
        int e = e0 + j * 1024 + tid;
        bkt[j] = -1;
        if (e < NE2) {
            int s, d;
            if (e < N_EDGE) { s = edge_ui[e]; d = edge_ui[N_EDGE + e]; }
            else { int f = e - N_EDGE; s = edge_iu[f]; d = N_ITEM + edge_iu[N_EDGE + f]; }
            bkt[j] = d >> BKT_SH;
            rec[j] = (unsigned int)s | ((unsigned int)(d & 511) << 16);
            rnk[j] = atomicAdd(&bcnt[bkt[j]], 1);
        }
    }
    __syncthreads();
    for (int i = tid; i < NBKT; i += 1024) {
        int c = bcnt[i];
        bpos[i] = c ? atomicAdd(&bcur[i], c) : 0;
    }
    __syncthreads();
#pragma unroll
    for (int j = 0; j < 8; ++j) {
        if (bkt[j] >= 0) records[bpos[bkt[j]] + rnk[j]] = rec[j];
    }
}

// ---------------------------------------------------------------------------
// Per-bucket CSR build: LDS counting-sort by dst within the bucket; emits off[].
// ---------------------------------------------------------------------------
__global__ __launch_bounds__(1024) void csr_build_kernel(
    const unsigned int* __restrict__ records, const int* __restrict__ bbase,
    unsigned short* __restrict__ csr, int* __restrict__ off)
{
    __shared__ int dcnt[512];
    __shared__ int sa[512], sb[512];
    __shared__ int dcur[512];
    __shared__ unsigned short stage[CAP];

    const int b    = blockIdx.x;
    const int tid  = threadIdx.x;
    const int base = bbase[b];
    const int nb   = bbase[b + 1] - base;

    if (tid < 512) dcnt[tid] = 0;
    __syncthreads();

    for (int i = tid; i < nb; i += 1024)
        atomicAdd(&dcnt[records[base + i] >> 16], 1);
    __syncthreads();

    int* pa = sa; int* pb = sb;
    if (tid < 512) pa[tid] = dcnt[tid];
    __syncthreads();
    for (int d = 1; d < 512; d <<= 1) {
        if (tid < 512) pb[tid] = pa[tid] + ((tid >= d) ? pa[tid - d] : 0);
        __syncthreads();
        int* t = pa; pa = pb; pb = t;
    }
    if (tid < 512) {
        int excl = pa[tid] - dcnt[tid];
        dcur[tid] = excl;
        int dst = b * 512 + tid;
        if (dst < NTOT) off[dst] = base + excl;
    }
    if (b == NBKT - 1 && tid == 0) off[NTOT] = NE2;
    __syncthreads();

    if (nb <= CAP) {
        for (int i = tid; i < nb; i += 1024) {
            unsigned int r = records[base + i];
            int p = atomicAdd(&dcur[r >> 16], 1);
            stage[p] = (unsigned short)r;
        }
        __syncthreads();
        for (int i = tid; i < nb; i += 1024) csr[base + i] = stage[i];
    } else {
        for (int i = tid; i < nb; i += 1024) {
            unsigned int r = records[base + i];
            int p = atomicAdd(&dcur[r >> 16], 1);
            csr[base + p] = (unsigned short)r;
        }
    }
}

// ---------------------------------------------------------------------------
// Aggregate (mean), DUAL-EDGE: one wave per dst row, free-running.
// Lanes 0-31 process even edges, 32-63 odd edges; lane owns dims
// [4*hl, 4*hl+3] via one uint2 (8B) load -> 2 edges per wave-load, 16 edges
// in flight at 8-pair unroll. Halves merged once via shfl_xor(32) at the end.
// Writes bf16 mean into d_out head halves (stride 256).
// ---------------------------------------------------------------------------
__global__ __launch_bounds__(256) void agg3_kernel(
    const unsigned short* __restrict__ T_user, const unsigned short* __restrict__ T_item,
    const int* __restrict__ off, const unsigned short* __restrict__ csr,
    unsigned short* __restrict__ dout_u16)
{
    int r = (blockIdx.x * blockDim.x + threadIdx.x) >> 6;
    if (r >= NTOT) return;
    const int lane = threadIdx.x & 63;
    const int h    = lane >> 5;     // edge parity handled by this lane
    const int hl   = lane & 31;     // dim group: dims 4*hl .. 4*hl+3
    const unsigned short* Tg;
    unsigned short* outp;
    if (r < N_ITEM) { Tg = T_user; outp = dout_u16 + (size_t)(N_USER + r) * 256; }
    else            { Tg = T_item; outp = dout_u16 + (size_t)(r - N_ITEM) * 256; }

    const int o0 = off[r], o1 = off[r + 1];
    const int deg = o1 - o0;
    const int co4 = hl * 4;
    float a0 = 0.f, a1 = 0.f, a2 = 0.f, a3 = 0.f;

    int i = o0;
    // main loop: 8 pairs = 16 edges per iteration, 8 gathers in flight/lane
    for (; i + 15 < o1; i += 16) {
        int s[8];
#pragma unroll
        for (int p = 0; p < 8; ++p) s[p] = csr[i + 2 * p + h];
#pragma unroll
        for (int p = 0; p < 8; ++p) {
            uint2 w = *reinterpret_cast<const uint2*>(Tg + (size_t)s[p] * 128 + co4);
            a0 += bf2f((unsigned short)w.x); a1 += bf2f((unsigned short)(w.x >> 16));
            a2 += bf2f((unsigned short)w.y); a3 += bf2f((unsigned short)(w.y >> 16));
        }
    }
    // pair tail
    for (; i + 1 < o1; i += 2) {
        int s = csr[i + h];
        uint2 w = *reinterpret_cast<const uint2*>(Tg + (size_t)s * 128 + co4);
        a0 += bf2f((unsigned short)w.x); a1 += bf2f((unsigned short)(w.x >> 16));
        a2 += bf2f((unsigned short)w.y); a3 += bf2f((unsigned short)(w.y >> 16));
    }
    // odd leftover edge: half 0 only
    if (i < o1 && h == 0) {
        int s = csr[i];
        uint2 w = *reinterpret_cast<const uint2*>(Tg + (size_t)s * 128 + co4);
        a0 += bf2f((unsigned short)w.x); a1 += bf2f((unsigned short)(w.x >> 16));
        a2 += bf2f((unsigned short)w.y); a3 += bf2f((unsigned short)(w.y >> 16));
    }

    // merge the two edge-parity halves (lane <-> lane+32 hold same dims)
    a0 += __shfl_xor(a0, 32);
    a1 += __shfl_xor(a1, 32);
    a2 += __shfl_xor(a2, 32);
    a3 += __shfl_xor(a3, 32);

    float sc = (deg > 0) ? 1.0f / (float)deg : 0.0f;
    if (h == 0) {
        unsigned int w0 = (unsigned int)f2bf(a0 * sc) | ((unsigned int)f2bf(a1 * sc) << 16);
        unsigned int w1 = (unsigned int)f2bf(a2 * sc) | ((unsigned int)f2bf(a3 * sc) << 16);
        *reinterpret_cast<uint2*>(outp + co4) = make_uint2(w0, w1);
    }
}

// ---------------------------------------------------------------------------
// MFMA finish (round-6 structure), head from d_out (stride 256, in-place
// row-aliased: bf16[r][256] == fp32[r][128] bytes; wave stores depend on all
// its loads; waves own disjoint rows), tail from compact self table Ts.
// ---------------------------------------------------------------------------
#define NB_FIN 782   // ceil(50000/64)

__global__ __launch_bounds__(256) void finish2c_kernel(
    unsigned short* dout_u16,
    const unsigned short* __restrict__ T_user, const unsigned short* __restrict__ T_item,
    const unsigned short* __restrict__ WfragUI, const unsigned short* __restrict__ WfragIU,
    const float* __restrict__ b_ui, const float* __restrict__ b_iu)
{
    const int b = blockIdx.x;
    const unsigned short *headBase, *Ts, *Wfrag;
    const float* bias;
    float* outp;
    int rowBase;
    if (b < NB_FIN) {
        headBase = dout_u16 + (size_t)N_USER * 256;
        Ts = T_item; Wfrag = WfragUI; bias = b_ui;
        outp = reinterpret_cast<float*>(dout_u16) + (size_t)N_USER * 128;
        rowBase = b * 64;
    } else {
        headBase = dout_u16;
        Ts = T_user; Wfrag = WfragIU; bias = b_iu;
        outp = reinterpret_cast<float*>(dout_u16);
        rowBase = (b - NB_FIN) * 64;
    }

    const int tid  = threadIdx.x;
    const int wave = tid >> 6;
    const int lane = tid & 63;
    const int kg   = lane >> 4;
    rowBase += wave * 16;

    int arow = rowBase + (lane & 15);
    int arow_c = (arow < 50000) ? arow : 49999;
    const unsigned short* head_ptr = headBase + (size_t)arow_c * 256 + kg * 8;
    const unsigned short* tail_ptr = Ts + (size_t)arow_c * 128 + kg * 8;

    f32x4 acc[8];
#pragma unroll
    for (int c = 0; c < 8; ++c) acc[c] = (f32x4){0.f, 0.f, 0.f, 0.f};

#pragma unroll
    for (int ks = 0; ks < 8; ++ks) {
        bf16x8 a;
        if (ks < 4) a = *reinterpret_cast<const bf16x8*>(head_ptr + ks * 32);       // agg (Wl)
        else        a = *reinterpret_cast<const bf16x8*>(tail_ptr + (ks - 4) * 32); // self (Wr)
        const unsigned short* bptr = Wfrag + ((size_t)(ks * 8) * 64 + lane) * 8;
#pragma unroll
        for (int c = 0; c < 8; ++c) {
            bf16x8 bb = *reinterpret_cast<const bf16x8*>(bptr + (size_t)c * 512);
            acc[c] = __builtin_amdgcn_mfma_f32_16x16x32_bf16(a, bb, acc[c], 0, 0, 0);
        }
    }

    const int orow0 = rowBase + kg * 4;
    const int ocol  = lane & 15;
#pragma unroll
    for (int c = 0; c < 8; ++c) {
        float bv = bias[c * 16 + ocol];
#pragma unroll
        for (int r = 0; r < 4; ++r) {
            int row = orow0 + r;
            if (row < 50000) outp[(size_t)row * 128 + c * 16 + ocol] = acc[c][r] + bv;
        }
    }
}

// ---------------------------------------------------------------------------
extern "C" void kernel_launch(void* const* d_in, const int* in_sizes, int n_in,
                              void* d_out, int out_size, void* d_ws, size_t ws_size,
                              hipStream_t stream) {
    const int*   user_ids = (const int*)d_in[0];
    const float* item_x   = (const float*)d_in[1];
    const int*   edge_ui  = (const int*)d_in[2];
    const int*   edge_iu  = (const int*)d_in[3];
    const float* user_emb = (const float*)d_in[4];
    const float* W_l_ui   = (const float*)d_in[5];
    const float* W_r_ui   = (const float*)d_in[6];
    const float* b_ui     = (const float*)d_in[7];
    const float* W_l_iu   = (const float*)d_in[8];
    const float* W_r_iu   = (const float*)d_in[9];
    const float* b_iu     = (const float*)d_in[10];

    unsigned short* dout_u16 = (unsigned short*)d_out;

    // Workspace (16B-aligned blocks first)
    unsigned short* WfragUI = (unsigned short*)d_ws;            // 32768 u16
    unsigned short* WfragIU = WfragUI + 32768;                  // 32768 u16
    unsigned short* T_user  = WfragIU + 32768;                  // 50000*128 u16 (12.8MB)
    unsigned short* T_item  = T_user + (size_t)N_USER * 128;    // 12.8MB
    unsigned int*   records = (unsigned int*)(T_item + (size_t)N_ITEM * 128);  // NE2 (6.4MB)
    unsigned short* csr     = (unsigned short*)(records + NE2); // NE2 (3.2MB)
    int* gcnt  = (int*)(csr + NE2);                             // NBKT
    int* bbase = gcnt + NBKT;                                   // NBKT+1
    int* bcur  = bbase + NBKT + 1;                              // NBKT
    int* off   = bcur + NBKT;                                   // NTOT+1

    hipMemsetAsync(gcnt, 0, NBKT * sizeof(int), stream);

    mega3_kernel<<<PACKA_BLOCKS + PACKW_BLOCKS + CNT_BLOCKS, 256, 0, stream>>>(
        user_emb, user_ids, item_x, edge_ui, edge_iu,
        W_l_ui, W_r_ui, W_l_iu, W_r_iu,
        T_user, T_item, WfragUI, WfragIU, gcnt);
    bucketscan_kernel<<<1, 256, 0, stream>>>(gcnt, bbase, bcur);
    scatter_records_kernel<<<B2_BLOCKS, 1024, 0, stream>>>(edge_ui, edge_iu, bcur, records);
    csr_build_kernel<<<NBKT, 1024, 0, stream>>>(records, bbase, csr, off);

    agg3_kernel<<<(NTOT * 64) / 256, 256, 0, stream>>>(T_user, T_item, off, csr, dout_u16);
    finish2c_kernel<<<2 * NB_FIN, 256, 0, stream>>>(
        dout_u16, T_user, T_item, WfragUI, WfragIU, b_ui, b_iu);
}